// Round 8
// baseline (252.707 us; speedup 1.0000x reference)
//
#include <hip/hip_runtime.h>

// Problem constants (from reference)
#define NN 50000
#define NE 800000
#define IN_F 128
#define H1_F 64
#define H2_F 32
#define OUT_F 40

// bucketized CSR build
#define BSH 7                    // bucket = dst >> 7  (128 nodes per bucket)
#define NBKT 391                 // ceil(50000 / 128)
#define CAPA 4032                // per-bucket capacity (avg 2046, >40 sigma margin)
#define CHUNK 4096               // edges per binA block
#define NCH ((NE + CHUNK - 1) / CHUNK)   // 196
#define NGEMM ((NN + 63) / 64)           // 782 gemm blocks in phase1

static inline int cdiv(int a, int b) { return (a + b - 1) / b; }

// pack: bkt(9) | src(16) | dloc(7)  — src < 50000 < 2^16, bkt < 391 < 2^9
__device__ __forceinline__ unsigned pack_e(int s, int d) {
    return ((unsigned)(d >> BSH) << 23) | ((unsigned)s << 7) | (unsigned)(d & 127);
}

// ---------------- phase 1: front GEMM (t = x @ W1, unscaled) + binA (bucket-bin edges) ----
struct GemmLDS { float Xs[64][33]; float Wsh[32][64]; };
struct BinALDS { int hist[512]; int incl[512]; int runSt[512]; int lcur[512]; int baseSh[512];
                 unsigned stage[CHUNK]; };

__global__ __launch_bounds__(256)
void phase1_k(const float* __restrict__ x, const float* __restrict__ W1,
              const int* __restrict__ src, const int* __restrict__ dst,
              unsigned* __restrict__ pairs, int* __restrict__ gCursor,
              float* __restrict__ t_out) {
    __shared__ union { GemmLDS g; BinALDS a; } lds;
    const int t = threadIdx.x;

    if (blockIdx.x < NGEMM) {
        // ---- register-tiled GEMM: 64 rows x 64 cols, K=128 in 4 k-tiles ----
        const int rowBase = blockIdx.x * 64;
        const int tc = t % 16;          // 16 col-threads x 4 cols
        const int tr = t / 16;          // 16 row-threads x 4 rows
        float acc[4][4];
        #pragma unroll
        for (int i = 0; i < 4; ++i)
            #pragma unroll
            for (int j = 0; j < 4; ++j) acc[i][j] = 0.0f;

        for (int k0 = 0; k0 < IN_F; k0 += 32) {
            for (int l = t; l < 64 * 8; l += 256) {          // 64 rows x 32 k / 4
                int r  = l / 8;
                int kk = (l % 8) * 4;
                float4 v = make_float4(0.f, 0.f, 0.f, 0.f);
                int gr = rowBase + r;
                if (gr < NN) v = *reinterpret_cast<const float4*>(x + (size_t)gr * IN_F + k0 + kk);
                lds.g.Xs[r][kk + 0] = v.x; lds.g.Xs[r][kk + 1] = v.y;
                lds.g.Xs[r][kk + 2] = v.z; lds.g.Xs[r][kk + 3] = v.w;
            }
            for (int l = t; l < 32 * 16; l += 256) {         // 32 k x 64 cols / 4
                int kk = l / 16;
                int c  = (l % 16) * 4;
                *reinterpret_cast<float4*>(&lds.g.Wsh[kk][c]) =
                    *reinterpret_cast<const float4*>(W1 + (size_t)(k0 + kk) * H1_F + c);
            }
            __syncthreads();
            #pragma unroll
            for (int kk = 0; kk < 32; ++kk) {
                float wv[4];
                *reinterpret_cast<float4*>(wv) =
                    *reinterpret_cast<const float4*>(&lds.g.Wsh[kk][tc * 4]);
                #pragma unroll
                for (int i = 0; i < 4; ++i) {
                    float a = lds.g.Xs[tr * 4 + i][kk];
                    acc[i][0] = fmaf(a, wv[0], acc[i][0]);
                    acc[i][1] = fmaf(a, wv[1], acc[i][1]);
                    acc[i][2] = fmaf(a, wv[2], acc[i][2]);
                    acc[i][3] = fmaf(a, wv[3], acc[i][3]);
                }
            }
            __syncthreads();
        }
        #pragma unroll
        for (int i = 0; i < 4; ++i) {
            int gr = rowBase + tr * 4 + i;
            if (gr < NN) {
                float4 v;
                v.x = acc[i][0]; v.y = acc[i][1]; v.z = acc[i][2]; v.w = acc[i][3];
                *reinterpret_cast<float4*>(t_out + (size_t)gr * H1_F + tc * 4) = v;
            }
        }
    } else {
        // ---- binA: bin one 4096-edge chunk by dst>>7, append runs to bucket regions ----
        const int e0 = (blockIdx.x - NGEMM) * CHUNK;
        const int n = min(CHUNK, NE - e0);
        lds.a.hist[t] = 0; lds.a.hist[t + 256] = 0;
        __syncthreads();
        for (int i = t; i < n; i += 256) {
            int d = dst[e0 + i];
            atomicAdd(&lds.a.hist[d >> BSH], 1);
        }
        __syncthreads();
        lds.a.incl[t] = lds.a.hist[t]; lds.a.incl[t + 256] = lds.a.hist[t + 256];
        __syncthreads();
        for (int off = 1; off < 512; off <<= 1) {
            int v0 = (t >= off) ? lds.a.incl[t - off] : 0;
            int v1 = (t + 256 >= off) ? lds.a.incl[t + 256 - off] : 0;
            __syncthreads();
            lds.a.incl[t] += v0; lds.a.incl[t + 256] += v1;
            __syncthreads();
        }
        lds.a.runSt[t]       = lds.a.incl[t] - lds.a.hist[t];
        lds.a.runSt[t + 256] = lds.a.incl[t + 256] - lds.a.hist[t + 256];
        lds.a.lcur[t]        = lds.a.runSt[t];
        lds.a.lcur[t + 256]  = lds.a.runSt[t + 256];
        __syncthreads();
        for (int i = t; i < n; i += 256) {
            int s = src[e0 + i], d = dst[e0 + i];
            int b = d >> BSH;
            int p = atomicAdd(&lds.a.lcur[b], 1);
            lds.a.stage[p] = pack_e(s, d);
        }
        for (int b = t; b < NBKT; b += 256) {
            int c = lds.a.hist[b];
            lds.a.baseSh[b] = c ? atomicAdd(&gCursor[b], c) : 0;
        }
        __syncthreads();
        for (int i = t; i < n; i += 256) {
            unsigned p = lds.a.stage[i];
            int b = (int)(p >> 23);
            int gp = lds.a.baseSh[b] + (i - lds.a.runSt[b]);
            if (gp < CAPA) pairs[(size_t)b * CAPA + gp] = p;   // overflow guard
        }
    }
}

// ---------------- binB: per-bucket histogram -> dinv + rowptr + csr scatter ----------------
__global__ __launch_bounds__(256)
void binB_k(const unsigned* __restrict__ pairs, const int* __restrict__ gCursor,
            int2* __restrict__ rowptr, float* __restrict__ dinv, int* __restrict__ csr) {
    const int b = blockIdx.x;
    const int nodeBase = b << BSH;
    const int nNodes = min(128, NN - nodeBase);
    int count = min(gCursor[b], CAPA);
    const int seg = b * CAPA;
    __shared__ int hist[128], incl[128], lcur[128];
    const int t = threadIdx.x;
    if (t < 128) hist[t] = 0;
    __syncthreads();
    const unsigned* bp = pairs + (size_t)b * CAPA;
    for (int i = t; i < count; i += 256) {
        atomicAdd(&hist[bp[i] & 127], 1);
    }
    __syncthreads();
    if (t < 128) incl[t] = hist[t];
    __syncthreads();
    for (int off = 1; off < 128; off <<= 1) {
        int v = (t < 128 && t >= off) ? incl[t - off] : 0;
        __syncthreads();
        if (t < 128) incl[t] += v;
        __syncthreads();
    }
    if (t < nNodes) {
        int e = seg + incl[t];
        rowptr[nodeBase + t] = make_int2(e - hist[t], e);
        dinv[nodeBase + t]   = rsqrtf((float)hist[t] + 1.0f);  // +1 self-loop
        lcur[t] = e - hist[t];
    }
    __syncthreads();
    for (int i = t; i < count; i += 256) {
        unsigned p = bp[i];
        int pos = atomicAdd(&lcur[p & 127], 1);
        csr[pos] = (int)((p >> 7) & 0xFFFFu);
    }
}

// ---------------- hop-1 pull (src-scaled): v[d] = dinv_d^2 * (dinv_d*t[d] + sum dinv_s*t[s]) ----
__global__ __launch_bounds__(256)
void pull1_k(const float* __restrict__ in, const int* __restrict__ csr,
             const int2* __restrict__ rowptr, const float* __restrict__ dinv,
             float* __restrict__ out) {
    const int t = threadIdx.x;
    const int node = blockIdx.x * 16 + t / 16;
    const int col  = (t % 16) * 4;
    if (node >= NN) return;
    const int2 rp = rowptr[node];
    const float dd = dinv[node];
    float4 s4 = *reinterpret_cast<const float4*>(in + (size_t)node * 64 + col);
    float4 a0, a1, a2, a3;
    a0.x = dd * s4.x; a0.y = dd * s4.y; a0.z = dd * s4.z; a0.w = dd * s4.w;
    a1 = make_float4(0.f, 0.f, 0.f, 0.f);
    a2 = make_float4(0.f, 0.f, 0.f, 0.f);
    a3 = make_float4(0.f, 0.f, 0.f, 0.f);
    int k = rp.x;
    for (; k + 3 < rp.y; k += 4) {
        int s0 = csr[k], s1 = csr[k + 1], s2 = csr[k + 2], s3 = csr[k + 3];
        float w0 = dinv[s0], w1 = dinv[s1], w2 = dinv[s2], w3 = dinv[s3];
        float4 v0 = *reinterpret_cast<const float4*>(in + (size_t)s0 * 64 + col);
        float4 v1 = *reinterpret_cast<const float4*>(in + (size_t)s1 * 64 + col);
        float4 v2 = *reinterpret_cast<const float4*>(in + (size_t)s2 * 64 + col);
        float4 v3 = *reinterpret_cast<const float4*>(in + (size_t)s3 * 64 + col);
        a0.x = fmaf(w0, v0.x, a0.x); a0.y = fmaf(w0, v0.y, a0.y);
        a0.z = fmaf(w0, v0.z, a0.z); a0.w = fmaf(w0, v0.w, a0.w);
        a1.x = fmaf(w1, v1.x, a1.x); a1.y = fmaf(w1, v1.y, a1.y);
        a1.z = fmaf(w1, v1.z, a1.z); a1.w = fmaf(w1, v1.w, a1.w);
        a2.x = fmaf(w2, v2.x, a2.x); a2.y = fmaf(w2, v2.y, a2.y);
        a2.z = fmaf(w2, v2.z, a2.z); a2.w = fmaf(w2, v2.w, a2.w);
        a3.x = fmaf(w3, v3.x, a3.x); a3.y = fmaf(w3, v3.y, a3.y);
        a3.z = fmaf(w3, v3.z, a3.z); a3.w = fmaf(w3, v3.w, a3.w);
    }
    for (; k < rp.y; ++k) {
        int s0 = csr[k];
        float w0 = dinv[s0];
        float4 v0 = *reinterpret_cast<const float4*>(in + (size_t)s0 * 64 + col);
        a0.x = fmaf(w0, v0.x, a0.x); a0.y = fmaf(w0, v0.y, a0.y);
        a0.z = fmaf(w0, v0.z, a0.z); a0.w = fmaf(w0, v0.w, a0.w);
    }
    const float sc = dd * dd;
    float4 r;
    r.x = (a0.x + a1.x + a2.x + a3.x) * sc;
    r.y = (a0.y + a1.y + a2.y + a3.y) * sc;
    r.z = (a0.z + a1.z + a2.z + a3.z) * sc;
    r.w = (a0.w + a1.w + a2.w + a3.w) * sc;
    *reinterpret_cast<float4*>(out + (size_t)node * 64 + col) = r;
}

// ---------------- hop-3 pull: u[d] = dinv_d^2 * (t2[d] + sum t2[s])  (width 32) ----------------
__global__ __launch_bounds__(256)
void pull32_k(const float* __restrict__ in, const int* __restrict__ csr,
              const int2* __restrict__ rowptr, const float* __restrict__ dinv,
              float* __restrict__ out) {
    const int t = threadIdx.x;
    const int node = blockIdx.x * 32 + t / 8;
    const int col  = (t % 8) * 4;
    if (node >= NN) return;
    const int2 rp = rowptr[node];
    float4 a0 = *reinterpret_cast<const float4*>(in + (size_t)node * 32 + col);
    float4 a1 = make_float4(0.f, 0.f, 0.f, 0.f);
    float4 a2 = make_float4(0.f, 0.f, 0.f, 0.f);
    float4 a3 = make_float4(0.f, 0.f, 0.f, 0.f);
    int k = rp.x;
    for (; k + 3 < rp.y; k += 4) {
        int s0 = csr[k], s1 = csr[k + 1], s2 = csr[k + 2], s3 = csr[k + 3];
        float4 v0 = *reinterpret_cast<const float4*>(in + (size_t)s0 * 32 + col);
        float4 v1 = *reinterpret_cast<const float4*>(in + (size_t)s1 * 32 + col);
        float4 v2 = *reinterpret_cast<const float4*>(in + (size_t)s2 * 32 + col);
        float4 v3 = *reinterpret_cast<const float4*>(in + (size_t)s3 * 32 + col);
        a0.x += v0.x; a0.y += v0.y; a0.z += v0.z; a0.w += v0.w;
        a1.x += v1.x; a1.y += v1.y; a1.z += v1.z; a1.w += v1.w;
        a2.x += v2.x; a2.y += v2.y; a2.z += v2.z; a2.w += v2.w;
        a3.x += v3.x; a3.y += v3.y; a3.z += v3.z; a3.w += v3.w;
    }
    for (; k < rp.y; ++k) {
        int s0 = csr[k];
        float4 v0 = *reinterpret_cast<const float4*>(in + (size_t)s0 * 32 + col);
        a0.x += v0.x; a0.y += v0.y; a0.z += v0.z; a0.w += v0.w;
    }
    float sc = dinv[node]; sc *= sc;
    float4 r;
    r.x = (a0.x + a1.x + a2.x + a3.x) * sc;
    r.y = (a0.y + a1.y + a2.y + a3.y) * sc;
    r.z = (a0.z + a1.z + a2.z + a3.z) * sc;
    r.w = (a0.w + a1.w + a2.w + a3.w) * sc;
    *reinterpret_cast<float4*>(out + (size_t)node * 32 + col) = r;
}

// ---------------- fused: hop-2 pull (+relu) + GEMM W2 + dinv scale ----------------
// h = relu(dinv_d*(v[d]+sum v[s]) + b1);  t2[d] = dinv_d * (h @ W2)   [64 -> 32]
__global__ __launch_bounds__(256)
void pullgemm2_k(const float* __restrict__ in, const int* __restrict__ csr,
                 const int2* __restrict__ rowptr, const float* __restrict__ dinv,
                 const float* __restrict__ b1, const float* __restrict__ W2,
                 float* __restrict__ outT) {
    __shared__ float hs[64][68];
    __shared__ float W2s[64][32];
    const int t = threadIdx.x;
    for (int i = t; i < 64 * 32 / 4; i += 256)
        reinterpret_cast<float4*>(&W2s[0][0])[i] = reinterpret_cast<const float4*>(W2)[i];
    const int nodeBase = blockIdx.x * 64;
    #pragma unroll
    for (int pass = 0; pass < 4; ++pass) {
        const int nb = pass * 16 + t / 16;
        const int node = nodeBase + nb;
        const int col = (t % 16) * 4;
        float4 r = make_float4(0.f, 0.f, 0.f, 0.f);
        if (node < NN) {
            const int2 rp = rowptr[node];
            float4 a0 = *reinterpret_cast<const float4*>(in + (size_t)node * 64 + col);
            float4 a1 = make_float4(0.f, 0.f, 0.f, 0.f);
            float4 a2 = make_float4(0.f, 0.f, 0.f, 0.f);
            float4 a3 = make_float4(0.f, 0.f, 0.f, 0.f);
            int k = rp.x;
            for (; k + 3 < rp.y; k += 4) {
                int s0 = csr[k], s1 = csr[k + 1], s2 = csr[k + 2], s3 = csr[k + 3];
                float4 v0 = *reinterpret_cast<const float4*>(in + (size_t)s0 * 64 + col);
                float4 v1 = *reinterpret_cast<const float4*>(in + (size_t)s1 * 64 + col);
                float4 v2 = *reinterpret_cast<const float4*>(in + (size_t)s2 * 64 + col);
                float4 v3 = *reinterpret_cast<const float4*>(in + (size_t)s3 * 64 + col);
                a0.x += v0.x; a0.y += v0.y; a0.z += v0.z; a0.w += v0.w;
                a1.x += v1.x; a1.y += v1.y; a1.z += v1.z; a1.w += v1.w;
                a2.x += v2.x; a2.y += v2.y; a2.z += v2.z; a2.w += v2.w;
                a3.x += v3.x; a3.y += v3.y; a3.z += v3.z; a3.w += v3.w;
            }
            for (; k < rp.y; ++k) {
                int s0 = csr[k];
                float4 v0 = *reinterpret_cast<const float4*>(in + (size_t)s0 * 64 + col);
                a0.x += v0.x; a0.y += v0.y; a0.z += v0.z; a0.w += v0.w;
            }
            const float sc = dinv[node];
            const float4 bv = *reinterpret_cast<const float4*>(b1 + col);
            r.x = fmaxf((a0.x + a1.x + a2.x + a3.x) * sc + bv.x, 0.f);
            r.y = fmaxf((a0.y + a1.y + a2.y + a3.y) * sc + bv.y, 0.f);
            r.z = fmaxf((a0.z + a1.z + a2.z + a3.z) * sc + bv.z, 0.f);
            r.w = fmaxf((a0.w + a1.w + a2.w + a3.w) * sc + bv.w, 0.f);
        }
        *reinterpret_cast<float4*>(&hs[nb][col]) = r;
    }
    __syncthreads();
    const int r = t / 4;
    const int c0 = (t % 4) * 8;
    float acc[8];
    #pragma unroll
    for (int j = 0; j < 8; ++j) acc[j] = 0.f;
    #pragma unroll 4
    for (int k = 0; k < 64; k += 4) {
        float4 av = *reinterpret_cast<const float4*>(&hs[r][k]);
        #pragma unroll
        for (int kk = 0; kk < 4; ++kk) {
            float a = (&av.x)[kk];
            float4 w0 = *reinterpret_cast<const float4*>(&W2s[k + kk][c0]);
            float4 w1 = *reinterpret_cast<const float4*>(&W2s[k + kk][c0 + 4]);
            acc[0] = fmaf(a, w0.x, acc[0]); acc[1] = fmaf(a, w0.y, acc[1]);
            acc[2] = fmaf(a, w0.z, acc[2]); acc[3] = fmaf(a, w0.w, acc[3]);
            acc[4] = fmaf(a, w1.x, acc[4]); acc[5] = fmaf(a, w1.y, acc[5]);
            acc[6] = fmaf(a, w1.z, acc[6]); acc[7] = fmaf(a, w1.w, acc[7]);
        }
    }
    const int node = nodeBase + r;
    if (node < NN) {
        const float sc = dinv[node];
        float4 o0, o1;
        o0.x = acc[0] * sc; o0.y = acc[1] * sc; o0.z = acc[2] * sc; o0.w = acc[3] * sc;
        o1.x = acc[4] * sc; o1.y = acc[5] * sc; o1.z = acc[6] * sc; o1.w = acc[7] * sc;
        *reinterpret_cast<float4*>(outT + (size_t)node * 32 + c0)     = o0;
        *reinterpret_cast<float4*>(outT + (size_t)node * 32 + c0 + 4) = o1;
    }
}

// ---------------- fused: hop-4 pull (+relu) -> emb, + final GEMM Wf -> logits ----------------
__global__ __launch_bounds__(256)
void pullgemmF_k(const float* __restrict__ in, const int* __restrict__ csr,
                 const int2* __restrict__ rowptr, const float* __restrict__ dinv,
                 const float* __restrict__ b2, const float* __restrict__ Wf,
                 const float* __restrict__ bf, float* __restrict__ embOut,
                 float* __restrict__ logits) {
    __shared__ float es[64][36];
    __shared__ float Wfs[32][40];
    __shared__ float bfs[40];
    const int t = threadIdx.x;
    for (int i = t; i < 32 * 40 / 4; i += 256)
        reinterpret_cast<float4*>(&Wfs[0][0])[i] = reinterpret_cast<const float4*>(Wf)[i];
    if (t < 40) bfs[t] = bf[t];
    const int nodeBase = blockIdx.x * 64;
    #pragma unroll
    for (int pass = 0; pass < 2; ++pass) {
        const int nb = pass * 32 + t / 8;
        const int node = nodeBase + nb;
        const int col = (t % 8) * 4;
        float4 r = make_float4(0.f, 0.f, 0.f, 0.f);
        if (node < NN) {
            const int2 rp = rowptr[node];
            float4 a0 = *reinterpret_cast<const float4*>(in + (size_t)node * 32 + col);
            float4 a1 = make_float4(0.f, 0.f, 0.f, 0.f);
            float4 a2 = make_float4(0.f, 0.f, 0.f, 0.f);
            float4 a3 = make_float4(0.f, 0.f, 0.f, 0.f);
            int k = rp.x;
            for (; k + 3 < rp.y; k += 4) {
                int s0 = csr[k], s1 = csr[k + 1], s2 = csr[k + 2], s3 = csr[k + 3];
                float4 v0 = *reinterpret_cast<const float4*>(in + (size_t)s0 * 32 + col);
                float4 v1 = *reinterpret_cast<const float4*>(in + (size_t)s1 * 32 + col);
                float4 v2 = *reinterpret_cast<const float4*>(in + (size_t)s2 * 32 + col);
                float4 v3 = *reinterpret_cast<const float4*>(in + (size_t)s3 * 32 + col);
                a0.x += v0.x; a0.y += v0.y; a0.z += v0.z; a0.w += v0.w;
                a1.x += v1.x; a1.y += v1.y; a1.z += v1.z; a1.w += v1.w;
                a2.x += v2.x; a2.y += v2.y; a2.z += v2.z; a2.w += v2.w;
                a3.x += v3.x; a3.y += v3.y; a3.z += v3.z; a3.w += v3.w;
            }
            for (; k < rp.y; ++k) {
                int s0 = csr[k];
                float4 v0 = *reinterpret_cast<const float4*>(in + (size_t)s0 * 32 + col);
                a0.x += v0.x; a0.y += v0.y; a0.z += v0.z; a0.w += v0.w;
            }
            const float sc = dinv[node];
            const float4 bv = *reinterpret_cast<const float4*>(b2 + col);
            r.x = fmaxf((a0.x + a1.x + a2.x + a3.x) * sc + bv.x, 0.f);
            r.y = fmaxf((a0.y + a1.y + a2.y + a3.y) * sc + bv.y, 0.f);
            r.z = fmaxf((a0.z + a1.z + a2.z + a3.z) * sc + bv.z, 0.f);
            r.w = fmaxf((a0.w + a1.w + a2.w + a3.w) * sc + bv.w, 0.f);
            *reinterpret_cast<float4*>(embOut + (size_t)node * 32 + col) = r;
        }
        *reinterpret_cast<float4*>(&es[nb][col]) = r;
    }
    __syncthreads();
    const int r = t / 4;
    const int c0 = (t % 4) * 10;
    float acc[10];
    #pragma unroll
    for (int j = 0; j < 10; ++j) acc[j] = bfs[c0 + j];
    #pragma unroll 4
    for (int k = 0; k < 32; k += 4) {
        float4 av = *reinterpret_cast<const float4*>(&es[r][k]);
        #pragma unroll
        for (int kk = 0; kk < 4; ++kk) {
            float a = (&av.x)[kk];
            #pragma unroll
            for (int j = 0; j < 10; ++j)
                acc[j] = fmaf(a, Wfs[k + kk][c0 + j], acc[j]);
        }
    }
    const int node = nodeBase + r;
    if (node < NN) {
        float* lp = logits + (size_t)node * 40 + c0;
        #pragma unroll
        for (int j = 0; j < 10; j += 2) {
            float2 o; o.x = acc[j]; o.y = acc[j + 1];
            *reinterpret_cast<float2*>(lp + j) = o;
        }
    }
}

extern "C" void kernel_launch(void* const* d_in, const int* in_sizes, int n_in,
                              void* d_out, int out_size, void* d_ws, size_t ws_size,
                              hipStream_t stream) {
    const float* x  = (const float*)d_in[0];
    const int*   ei = (const int*)d_in[1];
    const float* W1 = (const float*)d_in[2];
    const float* b1 = (const float*)d_in[3];
    const float* W2 = (const float*)d_in[4];
    const float* b2 = (const float*)d_in[5];
    const float* Wf = (const float*)d_in[6];
    const float* bf = (const float*)d_in[7];

    float* out    = (float*)d_out;
    float* embOut = out;                       // [N, 32]
    float* logits = out + (size_t)NN * H2_F;   // [N, 40]

    const int* src = ei;        // edge_index[0]
    const int* dst = ei + NE;   // edge_index[1]

    // workspace layout (16B-aligned blocks)
    float* ws      = (float*)d_ws;
    float*    dinv   = ws;                               // NN f32          (200000)
    int2*     rowptr = (int2*)(ws + NN);                 // NN int2         (400000B region -> 100000 ints)
    int*      csr    = (int*)(rowptr + NN);              // NBKT*CAPA i32   (padded, 6.3MB)
    int*      gCursor= csr + (size_t)NBKT * CAPA;        // NBKT i32 (+pad)
    float*    bufA   = (float*)(gCursor + 512);          // NN*64 f32 (t, then t2 reuses)
    float*    bufB   = bufA + (size_t)NN * 64;           // NN*64 f32 (v, then u reuses)
    unsigned* pairs  = (unsigned*)bufB;                  // NBKT*CAPA u32 (6.3MB, dead before pull1 writes bufB)

    // ---- CSR build + front GEMM ----
    hipMemsetAsync(gCursor, 0, NBKT * sizeof(int), stream);
    phase1_k<<<NGEMM + NCH, 256, 0, stream>>>(x, W1, src, dst, pairs, gCursor, bufA);
    binB_k<<<NBKT, 256, 0, stream>>>(pairs, gCursor, rowptr, dinv, csr);

    // ---- layer 1 ----
    pull1_k<<<cdiv(NN, 16), 256, 0, stream>>>(bufA, csr, rowptr, dinv, bufB);        // v
    pullgemm2_k<<<cdiv(NN, 64), 256, 0, stream>>>(bufB, csr, rowptr, dinv, b1, W2, bufA);  // t2

    // ---- layer 2 ----
    pull32_k<<<cdiv(NN, 32), 256, 0, stream>>>(bufA, csr, rowptr, dinv, bufB);       // u
    pullgemmF_k<<<cdiv(NN, 64), 256, 0, stream>>>(bufB, csr, rowptr, dinv, b2, Wf, bf, embOut, logits);
}